// Round 6
// baseline (175.249 us; speedup 1.0000x reference)
//
#include <hip/hip_runtime.h>
#include <cmath>

// Problem constants (fixed by the reference)
constexpr int T_DIM = 4096;
constexpr int H_DIM = 1024;
constexpr int E_DIM = 8;
constexpr int I_DIM = 512;   // 4096 / 8
constexpr int V_DIM = 32000;

typedef _Float16 half_t;
typedef __attribute__((ext_vector_type(8))) _Float16 halfx8;
typedef __attribute__((ext_vector_type(4))) _Float16 halfx4;
typedef __attribute__((ext_vector_type(4))) float floatx4;

// async global->LDS, 16 B per lane; LDS dest is wave-uniform base + lane*16
#define GLOAD16(g, l)                                                        \
    __builtin_amdgcn_global_load_lds(                                        \
        (const __attribute__((address_space(1))) void*)(g),                  \
        (__attribute__((address_space(3))) void*)(l), 16, 0, 0)

// ---------------------------------------------------------------------------
// Workspace layout (bytes)
// ---------------------------------------------------------------------------
constexpr size_t OFF_COUNTS = 0;                                          // E ints
constexpr size_t OFF_EID    = 1024;                                       // T ints (16 KB)
constexpr size_t OFF_TOKL   = OFF_EID + (size_t)T_DIM * 4;                // E*T ints (128 KB)
constexpr size_t OFF_XB     = OFF_TOKL + (size_t)E_DIM * T_DIM * 4;       // T*H f16 (8 MB)
constexpr size_t OFF_GUPT   = OFF_XB + (size_t)T_DIM * H_DIM * 2;         // E*2I*H f16 (16 MB)
constexpr size_t OFF_DOWNT  = OFF_GUPT + (size_t)E_DIM * 2 * I_DIM * H_DIM * 2; // E*H*I f16 (8 MB)
constexpr size_t OFF_INTER  = OFF_DOWNT + (size_t)E_DIM * H_DIM * I_DIM * 2;    // T*I f16 (4 MB)

// ---------------------------------------------------------------------------
// Routing phase A: expert_id[t] = argmax(one_hot(tid%8)*10 + mu@mu_w.T).
// One block per token; NO global atomics (4096 fetch-adds on 8 addresses
// serialize cross-XCD at ~100ns each = ~50 us, measured rounds 2-3).
// ---------------------------------------------------------------------------
__global__ __launch_bounds__(256) void route_logits_kernel(
    const float* __restrict__ mu, const int* __restrict__ token_ids,
    const float* __restrict__ mu_w, int* __restrict__ expert_id)
{
    const int t = blockIdx.x;
    const int tid = threadIdx.x;

    const float4 m = *(const float4*)&mu[(size_t)t * H_DIM + tid * 4];
    float acc[E_DIM];
#pragma unroll
    for (int e = 0; e < E_DIM; ++e) {
        const float4 w = *(const float4*)&mu_w[e * H_DIM + tid * 4];
        acc[e] = m.x * w.x + m.y * w.y + m.z * w.z + m.w * w.w;
    }
#pragma unroll
    for (int e = 0; e < E_DIM; ++e) {
#pragma unroll
        for (int off = 32; off > 0; off >>= 1)
            acc[e] += __shfl_down(acc[e], off, 64);
    }
    __shared__ float part[4][E_DIM];
    const int lane = tid & 63, w = tid >> 6;
    if (lane == 0) {
#pragma unroll
        for (int e = 0; e < E_DIM; ++e) part[w][e] = acc[e];
    }
    __syncthreads();
    if (tid == 0) {
        int tk = token_ids[t];
        tk = min(max(tk, 0), V_DIM - 1);
        const int be = tk & (E_DIM - 1);
        float best = -1e30f; int bi = 0;
#pragma unroll
        for (int e = 0; e < E_DIM; ++e) {
            const float c = part[0][e] + part[1][e] + part[2][e] + part[3][e]
                          + (e == be ? 10.f : 0.f);
            if (c > best) { best = c; bi = e; }  // strict > keeps first max (jnp.argmax)
        }
        expert_id[t] = bi;
    }
}

// ---------------------------------------------------------------------------
// Fused prep: z<8 gup-transpose, z in [8,16) down-transpose, z==16 x-convert,
// z==17 routing scatter (single active block, LDS-atomic histogram).
// Transposes: dst[e][n][k] = (f16) src[e][k][n], 64x64 tiles.
// ---------------------------------------------------------------------------
__global__ __launch_bounds__(256) void prep_kernel(
    const float* __restrict__ x, const float* __restrict__ gup,
    const float* __restrict__ down, half_t* __restrict__ xb,
    half_t* __restrict__ gupT, half_t* __restrict__ downT,
    const int* __restrict__ expert_id, int* __restrict__ counts,
    int* __restrict__ tok_list)
{
    const int z = blockIdx.z, tid = threadIdx.x;

    if (z == 17) {  // routing scatter: one block, LDS atomics (fast, 1 CU)
        if (blockIdx.x != 0 || blockIdx.y != 0) return;
        __shared__ int cnt[E_DIM];
        if (tid < E_DIM) cnt[tid] = 0;
        __syncthreads();
        for (int i = tid; i < T_DIM; i += 256) {
            const int e = expert_id[i];
            const int pos = atomicAdd(&cnt[e], 1);   // LDS atomic
            tok_list[e * T_DIM + pos] = i;
        }
        __syncthreads();
        if (tid < E_DIM) counts[tid] = cnt[tid];
        return;
    }

    if (z == 16) {  // convert x -> f16
        const int blk = blockIdx.y * 16 + blockIdx.x;   // 0..255
#pragma unroll
        for (int p = 0; p < 16; ++p) {
            const size_t i = (size_t)blk * 16384 + p * 1024 + tid * 4;
            const float4 v = *(const float4*)&x[i];
            halfx4 h = { (half_t)v.x, (half_t)v.y, (half_t)v.z, (half_t)v.w };
            *(halfx4*)&xb[i] = h;
        }
        return;
    }

    __shared__ float tile[64][65];
    const float* se;  half_t* de;  int K;
    if (z < 8) {
        se = gup + (size_t)z * H_DIM * (2 * I_DIM);
        de = gupT + (size_t)z * (2 * I_DIM) * H_DIM;
        K = H_DIM;                       // 1024; N = 1024
    } else {
        if (blockIdx.y >= 8) return;     // K=512 -> only 8 y-tiles
        const int e = z - 8;
        se = down + (size_t)e * I_DIM * H_DIM;
        de = downT + (size_t)e * H_DIM * I_DIM;
        K = I_DIM;                       // 512; N = 1024
    }
    constexpr int N = 1024;
    const int n0 = blockIdx.x * 64, k0 = blockIdx.y * 64;
    const int c4 = (tid & 15) * 4, r0 = tid >> 4;
#pragma unroll
    for (int p = 0; p < 4; ++p) {
        const int r = r0 + p * 16;
        const float4 v = *(const float4*)&se[(size_t)(k0 + r) * N + n0 + c4];
        tile[r][c4 + 0] = v.x; tile[r][c4 + 1] = v.y;
        tile[r][c4 + 2] = v.z; tile[r][c4 + 3] = v.w;
    }
    __syncthreads();
#pragma unroll
    for (int p = 0; p < 4; ++p) {
        const int n = r0 + p * 16;
        const int kc = (tid & 15) * 4;
        halfx4 h = { (half_t)tile[kc + 0][n], (half_t)tile[kc + 1][n],
                     (half_t)tile[kc + 2][n], (half_t)tile[kc + 3][n] };
        *(halfx4*)&de[(size_t)(n0 + n) * K + k0 + kc] = h;
    }
}

// ---------------------------------------------------------------------------
// MFMA GEMM 1: inter = silu(x@Wg) * (x@Wu).
// Block = 128 threads (2 waves), tile 32 tok x 64 inter-cols (B = 64g+64u).
// Grid (E, 8, 16) = 1024 blocks -> 4 blocks/CU: 4 independent barrier groups
// per CU so global_load_lds drains overlap (round-5 cfg had only 2, and 3584
// of its 4096 blocks were empty dispatches). m-stride loop handles any
// expert distribution (no assumption count<=512).
// blockIdx.x = expert -> XCD affinity (round-5 win, kept).
// ---------------------------------------------------------------------------
__global__ __launch_bounds__(128) void gemm1_mfma_kernel(
    const half_t* __restrict__ xb, const half_t* __restrict__ gupT,
    const int* __restrict__ counts, const int* __restrict__ tok_list,
    half_t* __restrict__ inter)
{
    const int e = blockIdx.x;              // expert == XCD affinity
    const int count = counts[e];
    const int n0 = blockIdx.y * 64;        // inter-col block

    __shared__ __align__(16) half_t As[32 * 64];
    __shared__ __align__(16) half_t Bs[128 * 64];
    __shared__ int toks[32];

    const int tid = threadIdx.x;
    const int lane = tid & 63;
    const int w = tid >> 6;                // wave 0/1
    const int lr = lane >> 3, lc = lane & 7;
    const int fm = lane & 15, q = lane >> 4;
    const int fm7 = fm & 7;

    const half_t* We = gupT + (size_t)e * (2 * I_DIM) * H_DIM;

    // B staging pointers: rows fixed for the whole kernel
    const half_t* bptr[8];
#pragma unroll
    for (int j = 0; j < 8; ++j) {          // B rows [w*64, w*64+64)
        const int n = w * 64 + j * 8 + lr;
        const int col = (n < 64) ? (n0 + n) : (I_DIM + n0 + (n - 64));
        const int cg = lc ^ (n & 7);
        bptr[j] = We + (size_t)col * H_DIM + cg * 8;
    }

    for (int m0 = blockIdx.z * 32; m0 < count; m0 += 512) {
        __syncthreads();                   // protect toks/LDS from prev iter
        if (tid < 32) {
            const int m = m0 + tid;
            toks[tid] = (m < count) ? tok_list[e * T_DIM + m] : -1;
        }
        __syncthreads();

        const half_t* aptr[2];
#pragma unroll
        for (int j = 0; j < 2; ++j) {      // A rows [w*16, w*16+16)
            const int r = w * 16 + j * 8 + lr;
            const int cg = lc ^ (r & 7);
            const int tk = toks[r];
            aptr[j] = xb + (size_t)(tk < 0 ? 0 : tk) * H_DIM + cg * 8;
        }

        const floatx4 fzero = {0.f, 0.f, 0.f, 0.f};
        floatx4 accg[2][2], accu[2][2];
#pragma unroll
        for (int i = 0; i < 2; ++i)
#pragma unroll
            for (int j = 0; j < 2; ++j) { accg[i][j] = fzero; accu[i][j] = fzero; }

        for (int k0 = 0; k0 < H_DIM; k0 += 64) {
#pragma unroll
            for (int j = 0; j < 2; ++j)
                GLOAD16(aptr[j] + k0, &As[(w * 16 + j * 8) * 64]);
#pragma unroll
            for (int j = 0; j < 8; ++j)
                GLOAD16(bptr[j] + k0, &Bs[(w * 64 + j * 8) * 64]);
            __syncthreads();

#pragma unroll
            for (int ks = 0; ks < 2; ++ks) {
                const int swz = ((ks * 4 + q) ^ fm7) * 8;   // halves
                const halfx8 a0 = *(const halfx8*)&As[fm * 64 + swz];
                const halfx8 a1 = *(const halfx8*)&As[(16 + fm) * 64 + swz];
#pragma unroll
                for (int ct = 0; ct < 2; ++ct) {
                    const int ng = w * 32 + ct * 16 + fm;
                    const halfx8 bg = *(const halfx8*)&Bs[ng * 64 + swz];
                    const halfx8 bu = *(const halfx8*)&Bs[(64 + ng) * 64 + swz];
                    accg[0][ct] = __builtin_amdgcn_mfma_f32_16x16x32_f16(a0, bg, accg[0][ct], 0, 0, 0);
                    accg[1][ct] = __builtin_amdgcn_mfma_f32_16x16x32_f16(a1, bg, accg[1][ct], 0, 0, 0);
                    accu[0][ct] = __builtin_amdgcn_mfma_f32_16x16x32_f16(a0, bu, accu[0][ct], 0, 0, 0);
                    accu[1][ct] = __builtin_amdgcn_mfma_f32_16x16x32_f16(a1, bu, accu[1][ct], 0, 0, 0);
                }
            }
            __syncthreads();
        }

        // C/D layout: col = lane&15, row = q*4 + reg
#pragma unroll
        for (int rt = 0; rt < 2; ++rt)
#pragma unroll
            for (int r = 0; r < 4; ++r) {
                const int row = 16 * rt + q * 4 + r;
                const int tk = toks[row];
                if (tk < 0) continue;
#pragma unroll
                for (int ct = 0; ct < 2; ++ct) {
                    const float g = accg[rt][ct][r];
                    const float u = accu[rt][ct][r];
                    const float s = g / (1.f + __expf(-g)) * u;
                    inter[(size_t)tk * I_DIM + n0 + w * 32 + ct * 16 + fm] = (half_t)s;
                }
            }
    }
}

// ---------------------------------------------------------------------------
// MFMA GEMM 2: out = inter @ down. Block = 128 threads, tile 32 tok x 128
// out-cols, same staging/swizzle/affinity scheme.
// ---------------------------------------------------------------------------
__global__ __launch_bounds__(128) void gemm2_mfma_kernel(
    const half_t* __restrict__ inter, const half_t* __restrict__ downT,
    const int* __restrict__ counts, const int* __restrict__ tok_list,
    float* __restrict__ out)
{
    const int e = blockIdx.x;              // expert == XCD affinity
    const int count = counts[e];
    const int n0 = blockIdx.y * 128;

    __shared__ __align__(16) half_t As[32 * 64];
    __shared__ __align__(16) half_t Bs[128 * 64];
    __shared__ int toks[32];

    const int tid = threadIdx.x;
    const int lane = tid & 63;
    const int w = tid >> 6;
    const int lr = lane >> 3, lc = lane & 7;
    const int fm = lane & 15, q = lane >> 4;
    const int fm7 = fm & 7;

    const half_t* De = downT + (size_t)e * H_DIM * I_DIM;

    const half_t* bptr[8];
#pragma unroll
    for (int j = 0; j < 8; ++j) {          // B rows [w*64, w*64+64)
        const int n = w * 64 + j * 8 + lr;
        const int cg = lc ^ (n & 7);
        bptr[j] = De + (size_t)(n0 + n) * I_DIM + cg * 8;
    }

    for (int m0 = blockIdx.z * 32; m0 < count; m0 += 512) {
        __syncthreads();
        if (tid < 32) {
            const int m = m0 + tid;
            toks[tid] = (m < count) ? tok_list[e * T_DIM + m] : -1;
        }
        __syncthreads();

        const half_t* aptr[2];
#pragma unroll
        for (int j = 0; j < 2; ++j) {
            const int r = w * 16 + j * 8 + lr;
            const int cg = lc ^ (r & 7);
            const int tk = toks[r];
            aptr[j] = inter + (size_t)(tk < 0 ? 0 : tk) * I_DIM + cg * 8;
        }

        const floatx4 fzero = {0.f, 0.f, 0.f, 0.f};
        floatx4 acc[2][4];
#pragma unroll
        for (int i = 0; i < 2; ++i)
#pragma unroll
            for (int j = 0; j < 4; ++j) acc[i][j] = fzero;

        for (int k0 = 0; k0 < I_DIM; k0 += 64) {
#pragma unroll
            for (int j = 0; j < 2; ++j)
                GLOAD16(aptr[j] + k0, &As[(w * 16 + j * 8) * 64]);
#pragma unroll
            for (int j = 0; j < 8; ++j)
                GLOAD16(bptr[j] + k0, &Bs[(w * 64 + j * 8) * 64]);
            __syncthreads();

#pragma unroll
            for (int ks = 0; ks < 2; ++ks) {
                const int swz = ((ks * 4 + q) ^ fm7) * 8;
                const halfx8 a0 = *(const halfx8*)&As[fm * 64 + swz];
                const halfx8 a1 = *(const halfx8*)&As[(16 + fm) * 64 + swz];
#pragma unroll
                for (int ct = 0; ct < 4; ++ct) {
                    const halfx8 b = *(const halfx8*)&Bs[(w * 64 + ct * 16 + fm) * 64 + swz];
                    acc[0][ct] = __builtin_amdgcn_mfma_f32_16x16x32_f16(a0, b, acc[0][ct], 0, 0, 0);
                    acc[1][ct] = __builtin_amdgcn_mfma_f32_16x16x32_f16(a1, b, acc[1][ct], 0, 0, 0);
                }
            }
            __syncthreads();
        }

#pragma unroll
        for (int rt = 0; rt < 2; ++rt)
#pragma unroll
            for (int r = 0; r < 4; ++r) {
                const int row = 16 * rt + q * 4 + r;
                const int tk = toks[row];
                if (tk < 0) continue;
#pragma unroll
                for (int ct = 0; ct < 4; ++ct)
                    out[(size_t)tk * H_DIM + n0 + w * 64 + ct * 16 + fm] = acc[rt][ct][r];
            }
    }
}

// ---------------------------------------------------------------------------
extern "C" void kernel_launch(void* const* d_in, const int* in_sizes, int n_in,
                              void* d_out, int out_size, void* d_ws, size_t ws_size,
                              hipStream_t stream)
{
    const float* x         = (const float*)d_in[0];
    const int*   token_ids = (const int*)  d_in[1];
    const float* mu        = (const float*)d_in[2];
    const float* gup       = (const float*)d_in[3];
    const float* down      = (const float*)d_in[4];
    const float* mu_w      = (const float*)d_in[5];
    float* out = (float*)d_out;

    char* ws = (char*)d_ws;
    int*    counts    = (int*)(ws + OFF_COUNTS);
    int*    expert_id = (int*)(ws + OFF_EID);
    int*    tok_list  = (int*)(ws + OFF_TOKL);
    half_t* xb        = (half_t*)(ws + OFF_XB);
    half_t* gupT      = (half_t*)(ws + OFF_GUPT);
    half_t* downT     = (half_t*)(ws + OFF_DOWNT);
    half_t* inter     = (half_t*)(ws + OFF_INTER);

    route_logits_kernel<<<T_DIM, 256, 0, stream>>>(mu, token_ids, mu_w, expert_id);
    prep_kernel<<<dim3(16, 16, 18), 256, 0, stream>>>(
        x, gup, down, xb, gupT, downT, expert_id, counts, tok_list);
    // expert on blockIdx.x: consecutive linear block ids round-robin the 8
    // XCDs, so expert e's blocks (and its L2 working set) pin to XCD e.
    gemm1_mfma_kernel<<<dim3(E_DIM, 8, 16), 128, 0, stream>>>(
        xb, gupT, counts, tok_list, inter);
    gemm2_mfma_kernel<<<dim3(E_DIM, 8, 16), 128, 0, stream>>>(
        inter, downT, counts, tok_list, out);
}

// Round 7
// 172.879 us; speedup vs baseline: 1.0137x; 1.0137x over previous
//
#include <hip/hip_runtime.h>
#include <cmath>

// Problem constants (fixed by the reference)
constexpr int T_DIM = 4096;
constexpr int H_DIM = 1024;
constexpr int E_DIM = 8;
constexpr int I_DIM = 512;   // 4096 / 8
constexpr int V_DIM = 32000;

typedef _Float16 half_t;
typedef __attribute__((ext_vector_type(8))) _Float16 halfx8;
typedef __attribute__((ext_vector_type(4))) _Float16 halfx4;
typedef __attribute__((ext_vector_type(4))) float floatx4;

// async global->LDS, 16 B per lane; LDS dest is wave-uniform base + lane*16
#define GLOAD16(g, l)                                                        \
    __builtin_amdgcn_global_load_lds(                                        \
        (const __attribute__((address_space(1))) void*)(g),                  \
        (__attribute__((address_space(3))) void*)(l), 16, 0, 0)

// Pipeline barriers: never drain vmcnt to 0 inside the K-loop.
// WAIT6: the 6 current-tile loads (issued one full iteration ago) are the
// oldest outstanding; vmcnt(6) retires exactly them. Memory clobber stops the
// compiler from caching LDS reads across or reordering GLOADs/ds_reads.
#define PIPE_BARRIER_WAIT6() asm volatile("s_waitcnt vmcnt(6)\n\ts_barrier" ::: "memory")
#define PIPE_BARRIER()       asm volatile("s_barrier" ::: "memory")

// ---------------------------------------------------------------------------
// Workspace layout (bytes)
// ---------------------------------------------------------------------------
constexpr size_t OFF_COUNTS = 0;                                          // E ints
constexpr size_t OFF_EID    = 1024;                                       // T ints (16 KB)
constexpr size_t OFF_TOKL   = OFF_EID + (size_t)T_DIM * 4;                // E*T ints (128 KB)
constexpr size_t OFF_XB     = OFF_TOKL + (size_t)E_DIM * T_DIM * 4;       // T*H f16 (8 MB)
constexpr size_t OFF_GUPT   = OFF_XB + (size_t)T_DIM * H_DIM * 2;         // E*2I*H f16 (16 MB)
constexpr size_t OFF_DOWNT  = OFF_GUPT + (size_t)E_DIM * 2 * I_DIM * H_DIM * 2; // E*H*I f16 (8 MB)
constexpr size_t OFF_INTER  = OFF_DOWNT + (size_t)E_DIM * H_DIM * I_DIM * 2;    // T*I f16 (4 MB)

// ---------------------------------------------------------------------------
// Routing phase A: expert_id[t] = argmax(one_hot(tid%8)*10 + mu@mu_w.T).
// One block per token; NO global atomics (4096 fetch-adds on 8 addresses
// serialize cross-XCD at ~100ns each = ~50 us, measured rounds 2-3).
// ---------------------------------------------------------------------------
__global__ __launch_bounds__(256) void route_logits_kernel(
    const float* __restrict__ mu, const int* __restrict__ token_ids,
    const float* __restrict__ mu_w, int* __restrict__ expert_id)
{
    const int t = blockIdx.x;
    const int tid = threadIdx.x;

    const float4 m = *(const float4*)&mu[(size_t)t * H_DIM + tid * 4];
    float acc[E_DIM];
#pragma unroll
    for (int e = 0; e < E_DIM; ++e) {
        const float4 w = *(const float4*)&mu_w[e * H_DIM + tid * 4];
        acc[e] = m.x * w.x + m.y * w.y + m.z * w.z + m.w * w.w;
    }
#pragma unroll
    for (int e = 0; e < E_DIM; ++e) {
#pragma unroll
        for (int off = 32; off > 0; off >>= 1)
            acc[e] += __shfl_down(acc[e], off, 64);
    }
    __shared__ float part[4][E_DIM];
    const int lane = tid & 63, w = tid >> 6;
    if (lane == 0) {
#pragma unroll
        for (int e = 0; e < E_DIM; ++e) part[w][e] = acc[e];
    }
    __syncthreads();
    if (tid == 0) {
        int tk = token_ids[t];
        tk = min(max(tk, 0), V_DIM - 1);
        const int be = tk & (E_DIM - 1);
        float best = -1e30f; int bi = 0;
#pragma unroll
        for (int e = 0; e < E_DIM; ++e) {
            const float c = part[0][e] + part[1][e] + part[2][e] + part[3][e]
                          + (e == be ? 10.f : 0.f);
            if (c > best) { best = c; bi = e; }  // strict > keeps first max (jnp.argmax)
        }
        expert_id[t] = bi;
    }
}

// ---------------------------------------------------------------------------
// Fused prep: z<8 gup-transpose, z in [8,16) down-transpose, z==16 x-convert,
// z==17 routing scatter (single active block, LDS-atomic histogram).
// Transposes: dst[e][n][k] = (f16) src[e][k][n], 64x64 tiles.
// ---------------------------------------------------------------------------
__global__ __launch_bounds__(256) void prep_kernel(
    const float* __restrict__ x, const float* __restrict__ gup,
    const float* __restrict__ down, half_t* __restrict__ xb,
    half_t* __restrict__ gupT, half_t* __restrict__ downT,
    const int* __restrict__ expert_id, int* __restrict__ counts,
    int* __restrict__ tok_list)
{
    const int z = blockIdx.z, tid = threadIdx.x;

    if (z == 17) {  // routing scatter: one block, LDS atomics (fast, 1 CU)
        if (blockIdx.x != 0 || blockIdx.y != 0) return;
        __shared__ int cnt[E_DIM];
        if (tid < E_DIM) cnt[tid] = 0;
        __syncthreads();
        for (int i = tid; i < T_DIM; i += 256) {
            const int e = expert_id[i];
            const int pos = atomicAdd(&cnt[e], 1);   // LDS atomic
            tok_list[e * T_DIM + pos] = i;
        }
        __syncthreads();
        if (tid < E_DIM) counts[tid] = cnt[tid];
        return;
    }

    if (z == 16) {  // convert x -> f16
        const int blk = blockIdx.y * 16 + blockIdx.x;   // 0..255
#pragma unroll
        for (int p = 0; p < 16; ++p) {
            const size_t i = (size_t)blk * 16384 + p * 1024 + tid * 4;
            const float4 v = *(const float4*)&x[i];
            halfx4 h = { (half_t)v.x, (half_t)v.y, (half_t)v.z, (half_t)v.w };
            *(halfx4*)&xb[i] = h;
        }
        return;
    }

    __shared__ float tile[64][65];
    const float* se;  half_t* de;  int K;
    if (z < 8) {
        se = gup + (size_t)z * H_DIM * (2 * I_DIM);
        de = gupT + (size_t)z * (2 * I_DIM) * H_DIM;
        K = H_DIM;                       // 1024; N = 1024
    } else {
        if (blockIdx.y >= 8) return;     // K=512 -> only 8 y-tiles
        const int e = z - 8;
        se = down + (size_t)e * I_DIM * H_DIM;
        de = downT + (size_t)e * H_DIM * I_DIM;
        K = I_DIM;                       // 512; N = 1024
    }
    constexpr int N = 1024;
    const int n0 = blockIdx.x * 64, k0 = blockIdx.y * 64;
    const int c4 = (tid & 15) * 4, r0 = tid >> 4;
#pragma unroll
    for (int p = 0; p < 4; ++p) {
        const int r = r0 + p * 16;
        const float4 v = *(const float4*)&se[(size_t)(k0 + r) * N + n0 + c4];
        tile[r][c4 + 0] = v.x; tile[r][c4 + 1] = v.y;
        tile[r][c4 + 2] = v.z; tile[r][c4 + 3] = v.w;
    }
    __syncthreads();
#pragma unroll
    for (int p = 0; p < 4; ++p) {
        const int n = r0 + p * 16;
        const int kc = (tid & 15) * 4;
        halfx4 h = { (half_t)tile[kc + 0][n], (half_t)tile[kc + 1][n],
                     (half_t)tile[kc + 2][n], (half_t)tile[kc + 3][n] };
        *(halfx4*)&de[(size_t)(n0 + n) * K + k0 + kc] = h;
    }
}

// ---------------------------------------------------------------------------
// MFMA GEMM 1: inter = silu(x@Wg) * (x@Wu).
// Round-5 tile (64 tok x 64 inter-cols, 256 thr, 4 waves 2x2) — B staging
// amortization preserved (round-6's 32-tok tile doubled B traffic, -16 us).
// NEW: double-buffered K-loop. Per iter: issue next tile's 6 GLOADs into the
// other buffer, s_waitcnt vmcnt(6) (retires only current tile's loads, issued
// a full iter ago -> latency hidden), raw s_barrier, compute, trailing
// s_barrier (write-after-read guard, no drain). Never vmcnt(0) in the loop.
// Grid (E, 8, 8) + m-stride loop: no empty dispatches, handles any skew.
// blockIdx.x = expert -> XCD affinity (round-5 win, kept).
// ---------------------------------------------------------------------------
__global__ __launch_bounds__(256) void gemm1_mfma_kernel(
    const half_t* __restrict__ xb, const half_t* __restrict__ gupT,
    const int* __restrict__ counts, const int* __restrict__ tok_list,
    half_t* __restrict__ inter)
{
    const int e = blockIdx.x;              // expert == XCD affinity
    const int count = counts[e];
    const int n0 = blockIdx.y * 64;        // gate col block

    __shared__ __align__(16) half_t As[2][64 * 64];
    __shared__ __align__(16) half_t Bs[2][128 * 64];
    __shared__ int toks[64];

    const int tid = threadIdx.x;
    const int lane = tid & 63;
    const int w = tid >> 6;
    const int lr = lane >> 3, lc = lane & 7;
    const int wr = w >> 1, wc = w & 1;
    const int fm = lane & 15, q = lane >> 4;
    const int fm7 = fm & 7;

    const half_t* We = gupT + (size_t)e * (2 * I_DIM) * H_DIM;

    // B staging pointers + LDS offsets (fixed for the whole kernel)
    const half_t* bptr[4];
    int blofs[4], alofs[2];
#pragma unroll
    for (int j = 0; j < 4; ++j) {                 // B rows [w*32, w*32+32)
        const int n = w * 32 + j * 8 + lr;
        const int col = (n < 64) ? (n0 + n) : (I_DIM + n0 + (n - 64));
        const int cg = lc ^ (n & 7);
        bptr[j] = We + (size_t)col * H_DIM + cg * 8;
        blofs[j] = (w * 32 + j * 8) * 64;
    }
#pragma unroll
    for (int j = 0; j < 2; ++j) alofs[j] = (w * 16 + j * 8) * 64;

    for (int m0 = blockIdx.z * 64; m0 < count; m0 += 512) {
        __syncthreads();                   // guard toks/LDS vs previous tile
        if (tid < 64) {
            const int m = m0 + tid;
            toks[tid] = (m < count) ? tok_list[e * T_DIM + m] : -1;
        }
        __syncthreads();

        const half_t* aptr[2];
#pragma unroll
        for (int j = 0; j < 2; ++j) {             // A rows [w*16, w*16+16)
            const int r = w * 16 + j * 8 + lr;
            const int cg = lc ^ (r & 7);
            const int tk = toks[r];
            aptr[j] = xb + (size_t)(tk < 0 ? 0 : tk) * H_DIM + cg * 8;
        }

        const floatx4 fzero = {0.f, 0.f, 0.f, 0.f};
        floatx4 accg[2][2], accu[2][2];
#pragma unroll
        for (int i = 0; i < 2; ++i)
#pragma unroll
            for (int j = 0; j < 2; ++j) { accg[i][j] = fzero; accu[i][j] = fzero; }

        // prologue: tile 0 -> buffer 0
#pragma unroll
        for (int j = 0; j < 2; ++j) GLOAD16(aptr[j], &As[0][alofs[j]]);
#pragma unroll
        for (int j = 0; j < 4; ++j) GLOAD16(bptr[j], &Bs[0][blofs[j]]);

        int k0 = 0;
        for (int it = 0; it < H_DIM / 64; ++it) {
            const int kn = (k0 + 64) & (H_DIM - 1);   // wraps harmlessly on last iter
            const int nb = (it + 1) & 1;
#pragma unroll
            for (int j = 0; j < 2; ++j) GLOAD16(aptr[j] + kn, &As[nb][alofs[j]]);
#pragma unroll
            for (int j = 0; j < 4; ++j) GLOAD16(bptr[j] + kn, &Bs[nb][blofs[j]]);

            PIPE_BARRIER_WAIT6();          // current tile resident everywhere

            const half_t* Ac = As[it & 1];
            const half_t* Bc = Bs[it & 1];
#pragma unroll
            for (int ks = 0; ks < 2; ++ks) {
                const int swz = ((ks * 4 + q) ^ fm7) * 8;   // halves
                const halfx8 a0 = *(const halfx8*)&Ac[(32 * wr + fm) * 64 + swz];
                const halfx8 a1 = *(const halfx8*)&Ac[(32 * wr + 16 + fm) * 64 + swz];
#pragma unroll
                for (int ct = 0; ct < 2; ++ct) {
                    const int ng = wc * 32 + ct * 16 + fm;
                    const halfx8 bg = *(const halfx8*)&Bc[ng * 64 + swz];
                    const halfx8 bu = *(const halfx8*)&Bc[(64 + ng) * 64 + swz];
                    accg[0][ct] = __builtin_amdgcn_mfma_f32_16x16x32_f16(a0, bg, accg[0][ct], 0, 0, 0);
                    accg[1][ct] = __builtin_amdgcn_mfma_f32_16x16x32_f16(a1, bg, accg[1][ct], 0, 0, 0);
                    accu[0][ct] = __builtin_amdgcn_mfma_f32_16x16x32_f16(a0, bu, accu[0][ct], 0, 0, 0);
                    accu[1][ct] = __builtin_amdgcn_mfma_f32_16x16x32_f16(a1, bu, accu[1][ct], 0, 0, 0);
                }
            }

            PIPE_BARRIER();                // all reads done before next writes
            k0 = kn;
        }

        // C/D layout: col = lane&15, row = q*4 + reg
#pragma unroll
        for (int rt = 0; rt < 2; ++rt)
#pragma unroll
            for (int r = 0; r < 4; ++r) {
                const int row = 32 * wr + 16 * rt + q * 4 + r;
                const int tk = toks[row];
                if (tk < 0) continue;
#pragma unroll
                for (int ct = 0; ct < 2; ++ct) {
                    const float g = accg[rt][ct][r];
                    const float u = accu[rt][ct][r];
                    const float s = g / (1.f + __expf(-g)) * u;
                    inter[(size_t)tk * I_DIM + n0 + wc * 32 + ct * 16 + fm] = (half_t)s;
                }
            }
    }
}

// ---------------------------------------------------------------------------
// MFMA GEMM 2: out = inter @ down. Round-5 tile (64 x 128), same
// double-buffered pipeline and grid scheme.
// ---------------------------------------------------------------------------
__global__ __launch_bounds__(256) void gemm2_mfma_kernel(
    const half_t* __restrict__ inter, const half_t* __restrict__ downT,
    const int* __restrict__ counts, const int* __restrict__ tok_list,
    float* __restrict__ out)
{
    const int e = blockIdx.x;              // expert == XCD affinity
    const int count = counts[e];
    const int n0 = blockIdx.y * 128;

    __shared__ __align__(16) half_t As[2][64 * 64];
    __shared__ __align__(16) half_t Bs[2][128 * 64];
    __shared__ int toks[64];

    const int tid = threadIdx.x;
    const int lane = tid & 63;
    const int w = tid >> 6;
    const int lr = lane >> 3, lc = lane & 7;
    const int wr = w >> 1, wc = w & 1;
    const int fm = lane & 15, q = lane >> 4;
    const int fm7 = fm & 7;

    const half_t* De = downT + (size_t)e * H_DIM * I_DIM;

    const half_t* bptr[4];
    int blofs[4], alofs[2];
#pragma unroll
    for (int j = 0; j < 4; ++j) {                 // B rows [w*32, w*32+32)
        const int n = w * 32 + j * 8 + lr;
        const int cg = lc ^ (n & 7);
        bptr[j] = De + (size_t)(n0 + n) * I_DIM + cg * 8;
        blofs[j] = (w * 32 + j * 8) * 64;
    }
#pragma unroll
    for (int j = 0; j < 2; ++j) alofs[j] = (w * 16 + j * 8) * 64;

    for (int m0 = blockIdx.z * 64; m0 < count; m0 += 512) {
        __syncthreads();
        if (tid < 64) {
            const int m = m0 + tid;
            toks[tid] = (m < count) ? tok_list[e * T_DIM + m] : -1;
        }
        __syncthreads();

        const half_t* aptr[2];
#pragma unroll
        for (int j = 0; j < 2; ++j) {
            const int r = w * 16 + j * 8 + lr;
            const int cg = lc ^ (r & 7);
            const int tk = toks[r];
            aptr[j] = inter + (size_t)(tk < 0 ? 0 : tk) * I_DIM + cg * 8;
        }

        const floatx4 fzero = {0.f, 0.f, 0.f, 0.f};
        floatx4 acc[2][4];
#pragma unroll
        for (int i = 0; i < 2; ++i)
#pragma unroll
            for (int j = 0; j < 4; ++j) acc[i][j] = fzero;

        // prologue: tile 0 -> buffer 0
#pragma unroll
        for (int j = 0; j < 2; ++j) GLOAD16(aptr[j], &As[0][alofs[j]]);
#pragma unroll
        for (int j = 0; j < 4; ++j) GLOAD16(bptr[j], &Bs[0][blofs[j]]);

        int k0 = 0;
        for (int it = 0; it < I_DIM / 64; ++it) {
            const int kn = (k0 + 64) & (I_DIM - 1);
            const int nb = (it + 1) & 1;
#pragma unroll
            for (int j = 0; j < 2; ++j) GLOAD16(aptr[j] + kn, &As[nb][alofs[j]]);
#pragma unroll
            for (int j = 0; j < 4; ++j) GLOAD16(bptr[j] + kn, &Bs[nb][blofs[j]]);

            PIPE_BARRIER_WAIT6();

            const half_t* Ac = As[it & 1];
            const half_t* Bc = Bs[it & 1];
#pragma unroll
            for (int ks = 0; ks < 2; ++ks) {
                const int swz = ((ks * 4 + q) ^ fm7) * 8;
                const halfx8 a0 = *(const halfx8*)&Ac[(32 * wr + fm) * 64 + swz];
                const halfx8 a1 = *(const halfx8*)&Ac[(32 * wr + 16 + fm) * 64 + swz];
#pragma unroll
                for (int ct = 0; ct < 4; ++ct) {
                    const halfx8 b = *(const halfx8*)&Bc[(wc * 64 + ct * 16 + fm) * 64 + swz];
                    acc[0][ct] = __builtin_amdgcn_mfma_f32_16x16x32_f16(a0, b, acc[0][ct], 0, 0, 0);
                    acc[1][ct] = __builtin_amdgcn_mfma_f32_16x16x32_f16(a1, b, acc[1][ct], 0, 0, 0);
                }
            }

            PIPE_BARRIER();
            k0 = kn;
        }

#pragma unroll
        for (int rt = 0; rt < 2; ++rt)
#pragma unroll
            for (int r = 0; r < 4; ++r) {
                const int row = 32 * wr + 16 * rt + q * 4 + r;
                const int tk = toks[row];
                if (tk < 0) continue;
#pragma unroll
                for (int ct = 0; ct < 4; ++ct)
                    out[(size_t)tk * H_DIM + n0 + wc * 64 + ct * 16 + fm] = acc[rt][ct][r];
            }
    }
}

// ---------------------------------------------------------------------------
extern "C" void kernel_launch(void* const* d_in, const int* in_sizes, int n_in,
                              void* d_out, int out_size, void* d_ws, size_t ws_size,
                              hipStream_t stream)
{
    const float* x         = (const float*)d_in[0];
    const int*   token_ids = (const int*)  d_in[1];
    const float* mu        = (const float*)d_in[2];
    const float* gup       = (const float*)d_in[3];
    const float* down      = (const float*)d_in[4];
    const float* mu_w      = (const float*)d_in[5];
    float* out = (float*)d_out;

    char* ws = (char*)d_ws;
    int*    counts    = (int*)(ws + OFF_COUNTS);
    int*    expert_id = (int*)(ws + OFF_EID);
    int*    tok_list  = (int*)(ws + OFF_TOKL);
    half_t* xb        = (half_t*)(ws + OFF_XB);
    half_t* gupT      = (half_t*)(ws + OFF_GUPT);
    half_t* downT     = (half_t*)(ws + OFF_DOWNT);
    half_t* inter     = (half_t*)(ws + OFF_INTER);

    route_logits_kernel<<<T_DIM, 256, 0, stream>>>(mu, token_ids, mu_w, expert_id);
    prep_kernel<<<dim3(16, 16, 18), 256, 0, stream>>>(
        x, gup, down, xb, gupT, downT, expert_id, counts, tok_list);
    // expert on blockIdx.x: consecutive linear block ids round-robin the 8
    // XCDs, so expert e's blocks (and its L2 working set) pin to XCD e.
    gemm1_mfma_kernel<<<dim3(E_DIM, 8, 8), 256, 0, stream>>>(
        xb, gupT, counts, tok_list, inter);
    gemm2_mfma_kernel<<<dim3(E_DIM, 8, 8), 256, 0, stream>>>(
        inter, downT, counts, tok_list, out);
}

// Round 8
// 158.605 us; speedup vs baseline: 1.1049x; 1.0900x over previous
//
#include <hip/hip_runtime.h>
#include <cmath>

// Problem constants (fixed by the reference)
constexpr int T_DIM = 4096;
constexpr int H_DIM = 1024;
constexpr int E_DIM = 8;
constexpr int I_DIM = 512;   // 4096 / 8
constexpr int V_DIM = 32000;

typedef _Float16 half_t;
typedef __attribute__((ext_vector_type(8))) _Float16 halfx8;
typedef __attribute__((ext_vector_type(4))) _Float16 halfx4;
typedef __attribute__((ext_vector_type(4))) float floatx4;

// async global->LDS, 16 B per lane; LDS dest is wave-uniform base + lane*16
#define GLOAD16(g, l)                                                        \
    __builtin_amdgcn_global_load_lds(                                        \
        (const __attribute__((address_space(1))) void*)(g),                  \
        (__attribute__((address_space(3))) void*)(l), 16, 0, 0)

// ---------------------------------------------------------------------------
// Workspace layout (bytes)
// ---------------------------------------------------------------------------
constexpr size_t OFF_COUNTS = 0;                                          // E ints
constexpr size_t OFF_EID    = 1024;                                       // T ints (16 KB)
constexpr size_t OFF_TOKL   = OFF_EID + (size_t)T_DIM * 4;                // E*T ints (128 KB)
constexpr size_t OFF_XB     = OFF_TOKL + (size_t)E_DIM * T_DIM * 4;       // T*H f16 (8 MB)
constexpr size_t OFF_GUPT   = OFF_XB + (size_t)T_DIM * H_DIM * 2;         // E*2I*H f16 (16 MB)
constexpr size_t OFF_DOWNT  = OFF_GUPT + (size_t)E_DIM * 2 * I_DIM * H_DIM * 2; // E*H*I f16 (8 MB)
constexpr size_t OFF_INTER  = OFF_DOWNT + (size_t)E_DIM * H_DIM * I_DIM * 2;    // T*I f16 (4 MB)

// ---------------------------------------------------------------------------
// Fused prep + routing logits (one launch, independent z-slices):
//   z <  8 : gup transpose  dst[e][n][k] = (f16) src[e][k][n], 64x64 tiles
//   z in [8,16): down transpose (same scheme)
//   z == 16: x -> f16 convert
//   z in [17,33): routing logits, one xy-block per token:
//                expert_id[t] = argmax(one_hot(tid%8)*10 + mu@mu_w.T)
// Routing uses NO global atomics (4096 fetch-adds on 8 addresses serialize
// cross-XCD at ~100ns each = ~50us, measured rounds 2-3). The scatter that
// consumes expert_id[] runs in a separate tiny kernel (needs all logits).
// Pipelining post-mortems (R6: smaller tiles doubled B staging, -16us; R7:
// dbuf + partial-vmcnt asm barriers defeated compiler scheduling, -14us) =>
// gemms stay at the round-5 optimum; this round only compacts the launch DAG.
// ---------------------------------------------------------------------------
__global__ __launch_bounds__(256) void prep_all_kernel(
    const float* __restrict__ x, const float* __restrict__ gup,
    const float* __restrict__ down, const float* __restrict__ mu,
    const int* __restrict__ token_ids, const float* __restrict__ mu_w,
    half_t* __restrict__ xb, half_t* __restrict__ gupT,
    half_t* __restrict__ downT, int* __restrict__ expert_id)
{
    const int z = blockIdx.z, tid = threadIdx.x;

    if (z >= 17) {  // routing logits: one block per token
        const int t = (z - 17) * 256 + blockIdx.y * 16 + blockIdx.x;

        const float4 m = *(const float4*)&mu[(size_t)t * H_DIM + tid * 4];
        float acc[E_DIM];
#pragma unroll
        for (int e = 0; e < E_DIM; ++e) {
            const float4 w = *(const float4*)&mu_w[e * H_DIM + tid * 4];
            acc[e] = m.x * w.x + m.y * w.y + m.z * w.z + m.w * w.w;
        }
#pragma unroll
        for (int e = 0; e < E_DIM; ++e) {
#pragma unroll
            for (int off = 32; off > 0; off >>= 1)
                acc[e] += __shfl_down(acc[e], off, 64);
        }
        __shared__ float part[4][E_DIM];
        const int lane = tid & 63, w = tid >> 6;
        if (lane == 0) {
#pragma unroll
            for (int e = 0; e < E_DIM; ++e) part[w][e] = acc[e];
        }
        __syncthreads();
        if (tid == 0) {
            int tk = token_ids[t];
            tk = min(max(tk, 0), V_DIM - 1);
            const int be = tk & (E_DIM - 1);
            float best = -1e30f; int bi = 0;
#pragma unroll
            for (int e = 0; e < E_DIM; ++e) {
                const float c = part[0][e] + part[1][e] + part[2][e] + part[3][e]
                              + (e == be ? 10.f : 0.f);
                if (c > best) { best = c; bi = e; }  // strict > = first max (jnp.argmax)
            }
            expert_id[t] = bi;
        }
        return;
    }

    if (z == 16) {  // convert x -> f16
        const int blk = blockIdx.y * 16 + blockIdx.x;   // 0..255
#pragma unroll
        for (int p = 0; p < 16; ++p) {
            const size_t i = (size_t)blk * 16384 + p * 1024 + tid * 4;
            const float4 v = *(const float4*)&x[i];
            halfx4 h = { (half_t)v.x, (half_t)v.y, (half_t)v.z, (half_t)v.w };
            *(halfx4*)&xb[i] = h;
        }
        return;
    }

    __shared__ float tile[64][65];
    const float* se;  half_t* de;  int K;
    if (z < 8) {
        se = gup + (size_t)z * H_DIM * (2 * I_DIM);
        de = gupT + (size_t)z * (2 * I_DIM) * H_DIM;
        K = H_DIM;                       // 1024; N = 1024
    } else {
        if (blockIdx.y >= 8) return;     // K=512 -> only 8 y-tiles
        const int e = z - 8;
        se = down + (size_t)e * I_DIM * H_DIM;
        de = downT + (size_t)e * H_DIM * I_DIM;
        K = I_DIM;                       // 512; N = 1024
    }
    constexpr int N = 1024;
    const int n0 = blockIdx.x * 64, k0 = blockIdx.y * 64;
    const int c4 = (tid & 15) * 4, r0 = tid >> 4;
#pragma unroll
    for (int p = 0; p < 4; ++p) {
        const int r = r0 + p * 16;
        const float4 v = *(const float4*)&se[(size_t)(k0 + r) * N + n0 + c4];
        tile[r][c4 + 0] = v.x; tile[r][c4 + 1] = v.y;
        tile[r][c4 + 2] = v.z; tile[r][c4 + 3] = v.w;
    }
    __syncthreads();
#pragma unroll
    for (int p = 0; p < 4; ++p) {
        const int n = r0 + p * 16;
        const int kc = (tid & 15) * 4;
        halfx4 h = { (half_t)tile[kc + 0][n], (half_t)tile[kc + 1][n],
                     (half_t)tile[kc + 2][n], (half_t)tile[kc + 3][n] };
        *(halfx4*)&de[(size_t)(n0 + n) * K + k0 + kc] = h;
    }
}

// ---------------------------------------------------------------------------
// Routing scatter: single block, LDS-atomic histogram (order within a bucket
// is irrelevant: each token's output rows are written by exactly one block).
// ---------------------------------------------------------------------------
__global__ __launch_bounds__(256) void scatter_kernel(
    const int* __restrict__ expert_id, int* __restrict__ counts,
    int* __restrict__ tok_list)
{
    const int tid = threadIdx.x;
    __shared__ int cnt[E_DIM];
    if (tid < E_DIM) cnt[tid] = 0;
    __syncthreads();
    for (int i = tid; i < T_DIM; i += 256) {
        const int e = expert_id[i];
        const int pos = atomicAdd(&cnt[e], 1);   // LDS atomic
        tok_list[e * T_DIM + pos] = i;
    }
    __syncthreads();
    if (tid < E_DIM) counts[tid] = cnt[tid];
}

// ---------------------------------------------------------------------------
// MFMA GEMM 1: inter = silu(x@Wg) * (x@Wu). Tile 64 tok x (64g + 64u), BK=64.
// EXACT round-5 configuration (158.8us total): single-buffer, compiler-
// scheduled waits, grid (E, 8, 64) with early-exit m-blocks.
// blockIdx.x = expert -> XCD affinity: expert e's 2MB weights + ~1MB token
// rows fit XCD e's 4MB L2 (the round-5 win).
// Staging via global_load_lds(16B), XOR-swizzled LDS (conflict-free frags).
// ---------------------------------------------------------------------------
__global__ __launch_bounds__(256) void gemm1_mfma_kernel(
    const half_t* __restrict__ xb, const half_t* __restrict__ gupT,
    const int* __restrict__ counts, const int* __restrict__ tok_list,
    half_t* __restrict__ inter)
{
    const int e = blockIdx.x;              // expert == XCD affinity
    const int count = counts[e];
    const int m0 = blockIdx.z * 64;
    if (m0 >= count) return;
    const int n0 = blockIdx.y * 64;        // gate col block

    __shared__ __align__(16) half_t As[64 * 64];
    __shared__ __align__(16) half_t Bs[128 * 64];
    __shared__ int toks[64];

    const int tid = threadIdx.x;
    if (tid < 64) {
        const int m = m0 + tid;
        toks[tid] = (m < count) ? tok_list[e * T_DIM + m] : -1;
    }
    __syncthreads();

    const half_t* We = gupT + (size_t)e * (2 * I_DIM) * H_DIM;

    const int lane = tid & 63;
    const int w = tid >> 6;
    const int lr = lane >> 3, lc = lane & 7;

    // per-lane staging pointers (row fixed across K-loop)
    const half_t* aptr[2]; const half_t* bptr[4];
    half_t *alds[2], *blds[4];
#pragma unroll
    for (int j = 0; j < 2; ++j) {                 // A rows [w*16, w*16+16)
        const int r = w * 16 + j * 8 + lr;
        const int cg = lc ^ (r & 7);
        const int tk = toks[r];
        aptr[j] = xb + (size_t)(tk < 0 ? 0 : tk) * H_DIM + cg * 8;
        alds[j] = &As[(w * 16 + j * 8) * 64];
    }
#pragma unroll
    for (int j = 0; j < 4; ++j) {                 // B rows [w*32, w*32+32)
        const int n = w * 32 + j * 8 + lr;
        const int col = (n < 64) ? (n0 + n) : (I_DIM + n0 + (n - 64));
        const int cg = lc ^ (n & 7);
        bptr[j] = We + (size_t)col * H_DIM + cg * 8;
        blds[j] = &Bs[(w * 32 + j * 8) * 64];
    }

    const floatx4 fzero = {0.f, 0.f, 0.f, 0.f};
    floatx4 accg[2][2], accu[2][2];
#pragma unroll
    for (int i = 0; i < 2; ++i)
#pragma unroll
        for (int j = 0; j < 2; ++j) { accg[i][j] = fzero; accu[i][j] = fzero; }

    const int wr = w >> 1, wc = w & 1;
    const int fm = lane & 15, q = lane >> 4;
    const int fm7 = fm & 7;

    for (int k0 = 0; k0 < H_DIM; k0 += 64) {
#pragma unroll
        for (int j = 0; j < 2; ++j) GLOAD16(aptr[j] + k0, alds[j]);
#pragma unroll
        for (int j = 0; j < 4; ++j) GLOAD16(bptr[j] + k0, blds[j]);
        __syncthreads();

#pragma unroll
        for (int ks = 0; ks < 2; ++ks) {
            const int swz = ((ks * 4 + q) ^ fm7) * 8;   // halves
            const halfx8 a0 = *(const halfx8*)&As[(32 * wr + fm) * 64 + swz];
            const halfx8 a1 = *(const halfx8*)&As[(32 * wr + 16 + fm) * 64 + swz];
#pragma unroll
            for (int ct = 0; ct < 2; ++ct) {
                const int ng = wc * 32 + ct * 16 + fm;
                const halfx8 bg = *(const halfx8*)&Bs[ng * 64 + swz];
                const halfx8 bu = *(const halfx8*)&Bs[(64 + ng) * 64 + swz];
                accg[0][ct] = __builtin_amdgcn_mfma_f32_16x16x32_f16(a0, bg, accg[0][ct], 0, 0, 0);
                accg[1][ct] = __builtin_amdgcn_mfma_f32_16x16x32_f16(a1, bg, accg[1][ct], 0, 0, 0);
                accu[0][ct] = __builtin_amdgcn_mfma_f32_16x16x32_f16(a0, bu, accu[0][ct], 0, 0, 0);
                accu[1][ct] = __builtin_amdgcn_mfma_f32_16x16x32_f16(a1, bu, accu[1][ct], 0, 0, 0);
            }
        }
        __syncthreads();
    }

    // C/D layout: col = lane&15, row = q*4 + reg
#pragma unroll
    for (int rt = 0; rt < 2; ++rt)
#pragma unroll
        for (int r = 0; r < 4; ++r) {
            const int row = 32 * wr + 16 * rt + q * 4 + r;
            const int tk = toks[row];
            if (tk < 0) continue;
#pragma unroll
            for (int ct = 0; ct < 2; ++ct) {
                const float g = accg[rt][ct][r];
                const float u = accu[rt][ct][r];
                const float s = g / (1.f + __expf(-g)) * u;
                inter[(size_t)tk * I_DIM + n0 + wc * 32 + ct * 16 + fm] = (half_t)s;
            }
        }
}

// ---------------------------------------------------------------------------
// MFMA GEMM 2: out = inter @ down. Tile 64 x 128, BK=64, same staging scheme.
// EXACT round-5 configuration. Same expert==blockIdx.x XCD-affinity grid.
// ---------------------------------------------------------------------------
__global__ __launch_bounds__(256) void gemm2_mfma_kernel(
    const half_t* __restrict__ inter, const half_t* __restrict__ downT,
    const int* __restrict__ counts, const int* __restrict__ tok_list,
    float* __restrict__ out)
{
    const int e = blockIdx.x;              // expert == XCD affinity
    const int count = counts[e];
    const int m0 = blockIdx.z * 64;
    if (m0 >= count) return;
    const int n0 = blockIdx.y * 128;

    __shared__ __align__(16) half_t As[64 * 64];
    __shared__ __align__(16) half_t Bs[128 * 64];
    __shared__ int toks[64];

    const int tid = threadIdx.x;
    if (tid < 64) {
        const int m = m0 + tid;
        toks[tid] = (m < count) ? tok_list[e * T_DIM + m] : -1;
    }
    __syncthreads();

    const half_t* De = downT + (size_t)e * H_DIM * I_DIM;

    const int lane = tid & 63;
    const int w = tid >> 6;
    const int lr = lane >> 3, lc = lane & 7;

    const half_t* aptr[2]; const half_t* bptr[4];
    half_t *alds[2], *blds[4];
#pragma unroll
    for (int j = 0; j < 2; ++j) {
        const int r = w * 16 + j * 8 + lr;
        const int cg = lc ^ (r & 7);
        const int tk = toks[r];
        aptr[j] = inter + (size_t)(tk < 0 ? 0 : tk) * I_DIM + cg * 8;
        alds[j] = &As[(w * 16 + j * 8) * 64];
    }
#pragma unroll
    for (int j = 0; j < 4; ++j) {
        const int n = w * 32 + j * 8 + lr;
        const int cg = lc ^ (n & 7);
        bptr[j] = De + (size_t)(n0 + n) * I_DIM + cg * 8;
        blds[j] = &Bs[(w * 32 + j * 8) * 64];
    }

    const floatx4 fzero = {0.f, 0.f, 0.f, 0.f};
    floatx4 acc[2][4];
#pragma unroll
    for (int i = 0; i < 2; ++i)
#pragma unroll
        for (int j = 0; j < 4; ++j) acc[i][j] = fzero;

    const int wr = w >> 1, wc = w & 1;
    const int fm = lane & 15, q = lane >> 4;
    const int fm7 = fm & 7;

    for (int k0 = 0; k0 < I_DIM; k0 += 64) {
#pragma unroll
        for (int j = 0; j < 2; ++j) GLOAD16(aptr[j] + k0, alds[j]);
#pragma unroll
        for (int j = 0; j < 4; ++j) GLOAD16(bptr[j] + k0, blds[j]);
        __syncthreads();

#pragma unroll
        for (int ks = 0; ks < 2; ++ks) {
            const int swz = ((ks * 4 + q) ^ fm7) * 8;
            const halfx8 a0 = *(const halfx8*)&As[(32 * wr + fm) * 64 + swz];
            const halfx8 a1 = *(const halfx8*)&As[(32 * wr + 16 + fm) * 64 + swz];
#pragma unroll
            for (int ct = 0; ct < 4; ++ct) {
                const halfx8 b = *(const halfx8*)&Bs[(wc * 64 + ct * 16 + fm) * 64 + swz];
                acc[0][ct] = __builtin_amdgcn_mfma_f32_16x16x32_f16(a0, b, acc[0][ct], 0, 0, 0);
                acc[1][ct] = __builtin_amdgcn_mfma_f32_16x16x32_f16(a1, b, acc[1][ct], 0, 0, 0);
            }
        }
        __syncthreads();
    }

#pragma unroll
    for (int rt = 0; rt < 2; ++rt)
#pragma unroll
        for (int r = 0; r < 4; ++r) {
            const int row = 32 * wr + 16 * rt + q * 4 + r;
            const int tk = toks[row];
            if (tk < 0) continue;
#pragma unroll
            for (int ct = 0; ct < 4; ++ct)
                out[(size_t)tk * H_DIM + n0 + wc * 64 + ct * 16 + fm] = acc[rt][ct][r];
        }
}

// ---------------------------------------------------------------------------
extern "C" void kernel_launch(void* const* d_in, const int* in_sizes, int n_in,
                              void* d_out, int out_size, void* d_ws, size_t ws_size,
                              hipStream_t stream)
{
    const float* x         = (const float*)d_in[0];
    const int*   token_ids = (const int*)  d_in[1];
    const float* mu        = (const float*)d_in[2];
    const float* gup       = (const float*)d_in[3];
    const float* down      = (const float*)d_in[4];
    const float* mu_w      = (const float*)d_in[5];
    float* out = (float*)d_out;

    char* ws = (char*)d_ws;
    int*    counts    = (int*)(ws + OFF_COUNTS);
    int*    expert_id = (int*)(ws + OFF_EID);
    int*    tok_list  = (int*)(ws + OFF_TOKL);
    half_t* xb        = (half_t*)(ws + OFF_XB);
    half_t* gupT      = (half_t*)(ws + OFF_GUPT);
    half_t* downT     = (half_t*)(ws + OFF_DOWNT);
    half_t* inter     = (half_t*)(ws + OFF_INTER);

    // One launch covers transposes + convert + routing logits (independent
    // z-slices); only the tiny scatter needs all logits done first.
    prep_all_kernel<<<dim3(16, 16, 33), 256, 0, stream>>>(
        x, gup, down, mu, token_ids, mu_w, xb, gupT, downT, expert_id);
    scatter_kernel<<<1, 256, 0, stream>>>(expert_id, counts, tok_list);
    // expert on blockIdx.x: consecutive linear block ids round-robin the 8
    // XCDs, so expert e's blocks (and its L2 working set) pin to XCD e.
    gemm1_mfma_kernel<<<dim3(E_DIM, 8, T_DIM / 64), 256, 0, stream>>>(
        xb, gupT, counts, tok_list, inter);
    gemm2_mfma_kernel<<<dim3(E_DIM, 8, T_DIM / 64), 256, 0, stream>>>(
        inter, downT, counts, tok_list, out);
}